// Round 9
// baseline (1238.174 us; speedup 1.0000x reference)
//
#include <hip/hip_runtime.h>
#include <hip/hip_bf16.h>

#define NCB 16
#define CS 256
#define HD 384
#define PD 2048
#define NROW 16384
#define NH 6144      // NCB*HD
#define LSR 5760     // (NCB-1)*HD  rows of linear_self
#define LSC 3840     // (NCB-1)*CS  cols of linear_self
#define SA_ROWS 32
#define SA_NBLK (NROW / SA_ROWS)   // 512
#define GNT (PD / 64)              // 32 K-tiles for gemm1

typedef __bf16 bf16x8 __attribute__((ext_vector_type(8)));
typedef float f32x4 __attribute__((ext_vector_type(4)));
typedef int int4v __attribute__((ext_vector_type(4)));

__device__ __forceinline__ unsigned short f2bf(float f) {
  unsigned u = __builtin_bit_cast(unsigned, f);
  u = (u + 0x7fffu + ((u >> 16) & 1u)) >> 16;
  return (unsigned short)u;
}
__device__ __forceinline__ float bf2f(unsigned short h) {
  unsigned u = ((unsigned)h) << 16;
  return __builtin_bit_cast(float, u);
}

__device__ __forceinline__ void gload16(void* lds, const void* g) {
  __builtin_amdgcn_global_load_lds(
      (const __attribute__((address_space(1))) unsigned int*)g,
      (__attribute__((address_space(3))) unsigned int*)lds, 16, 0, 0);
}

// ---------------- fp32 -> bf16 conversion ----------------
__global__ void k_f2b(const float* __restrict__ in, unsigned short* __restrict__ out, int n4) {
  for (int i = blockIdx.x * 256 + threadIdx.x; i < n4; i += gridDim.x * 256) {
    float4 v = ((const float4*)in)[i];
    ushort4 o;
    o.x = f2bf(v.x); o.y = f2bf(v.y); o.z = f2bf(v.z); o.w = f2bf(v.w);
    ((ushort4*)out)[i] = o;
  }
}

// ---------------- transpose linear_self (5760x3840 f32) -> T (3840x5760 bf16) ----------------
__global__ __launch_bounds__(256) void k_transpose(const float* __restrict__ LS,
                                                   unsigned short* __restrict__ T) {
  __shared__ float tile[32][33];
  int tx = threadIdx.x & 31, ty = threadIdx.x >> 5;
  int c0 = blockIdx.x * 32;  // col of LS = row of T
  int r0 = blockIdx.y * 32;  // row of LS = col of T
  for (int i = ty; i < 32; i += 8)
    tile[i][tx] = LS[(size_t)(r0 + i) * LSC + c0 + tx];
  __syncthreads();
  for (int i = ty; i < 32; i += 8)
    T[(size_t)(c0 + i) * LSR + r0 + tx] = f2bf(tile[tx][i]);
}

// ---------------- count valid[:,0] ----------------
__global__ void k_count(const int* __restrict__ ci, float* __restrict__ out) {
  int n = blockIdx.x * 256 + threadIdx.x;
  float v = (n < NROW && ci[(size_t)n * NCB] >= 0) ? 1.f : 0.f;
  #pragma unroll
  for (int m = 1; m < 64; m <<= 1) v += __shfl_xor(v, m);
  if ((threadIdx.x & 63) == 0) atomicAdd(out + 1, v);
}

// ---------------- GEMM1: 256x256 tile, BK=64, 8 waves, counted vmcnt ----------------
// r7 skeleton + m201-style fine phases: each 32-MFMA window split into two
// barrier-fenced 16-MFMA sub-phases (reads fenced so compiler can't hoist).
__global__ __launch_bounds__(512, 2) void k_gemm1(
    const unsigned short* __restrict__ A,   // predictor bf16 [NROW][PD]
    const unsigned short* __restrict__ B,   // W1 bf16 [NH][PD]
    const float* __restrict__ b1,
    unsigned short* __restrict__ H) {       // out [NROW][NH]
  __shared__ int4 Al[2][2][1024];   // 64 KB
  __shared__ int4 Bl[2][2][1024];   // 64 KB

  const int tid = threadIdx.x;
  const int lane = tid & 63;
  const int w = tid >> 6;             // 0..7
  const int wr = w >> 2, wc = w & 3;  // wave grid 2(M) x 4(N)
  const int l15 = lane & 15, hi = lane >> 4;
  const int w64 = tid & ~63;

  // XCD swizzle: grid 1536 = 64 mt x 24 nt; each XCD owns 3 nt (3MB B -> L2)
  const int bid = blockIdx.x;
  const int xcd = bid & 7, p = bid >> 3;   // p in [0,192)
  const int nt = xcd * 3 + p % 3;
  const int mt = p / 3;
  const int tm = mt * 256, tn = nt * 256;

  f32x4 acc[8][4] = {};

  auto STAGE = [&](int buf, int t, int kh) {
    const int kb = t * 64 + kh * 32;
    #pragma unroll
    for (int g = 0; g < 2; ++g) {
      const int slot = g * 512 + tid;
      const int row = slot >> 2;                       // 0..255
      const int lc = (slot & 3) ^ ((row >> 1) & 3);    // inverse-swizzled source col
      gload16(&Al[buf][kh][g * 512 + w64], A + (size_t)(tm + row) * PD + kb + lc * 8);
      gload16(&Bl[buf][kh][g * 512 + w64], B + (size_t)(tn + row) * PD + kb + lc * 8);
    }
  };

  // prologue: t0.kh0, t0.kh1, t1.kh0 -> 12 loads; wait oldest 4 (t0.kh0)
  STAGE(0, 0, 0);
  STAGE(0, 0, 1);
  STAGE(1, 1, 0);
  asm volatile("s_waitcnt vmcnt(8)" ::: "memory");
  __builtin_amdgcn_s_barrier();

  for (int t = 0; t < GNT; ++t) {
    const int buf = t & 1;
    #pragma unroll
    for (int kh = 0; kh < 2; ++kh) {
      int4 af[8], bfr[4];
      // ---- sub-phase A: reads B(4) + A mi0-3 (4), stage, bar, 16 MFMA, bar
      #pragma unroll
      for (int ni = 0; ni < 4; ++ni) {
        const int row = wc * 64 + ni * 16 + l15;
        bfr[ni] = Bl[buf][kh][row * 4 + (hi ^ ((row >> 1) & 3))];
      }
      #pragma unroll
      for (int mi = 0; mi < 4; ++mi) {
        const int row = wr * 128 + mi * 16 + l15;
        af[mi] = Al[buf][kh][row * 4 + (hi ^ ((row >> 1) & 3))];
      }
      if (kh == 0) {
        if (t + 1 < GNT) STAGE(buf ^ 1, t + 1, 1);
      } else {
        if (t + 2 < GNT) STAGE(buf, t + 2, 0);
      }
      __builtin_amdgcn_s_barrier();
      __builtin_amdgcn_s_setprio(1);
      #pragma unroll
      for (int mi = 0; mi < 4; ++mi)
        #pragma unroll
        for (int ni = 0; ni < 4; ++ni)
          acc[mi][ni] = __builtin_amdgcn_mfma_f32_16x16x32_bf16(
              __builtin_bit_cast(bf16x8, af[mi]), __builtin_bit_cast(bf16x8, bfr[ni]),
              acc[mi][ni], 0, 0, 0);
      __builtin_amdgcn_s_setprio(0);
      __builtin_amdgcn_s_barrier();
      // ---- sub-phase B: reads A mi4-7 (4), bar, 16 MFMA, vmcnt, bar
      #pragma unroll
      for (int mi = 4; mi < 8; ++mi) {
        const int row = wr * 128 + mi * 16 + l15;
        af[mi] = Al[buf][kh][row * 4 + (hi ^ ((row >> 1) & 3))];
      }
      __builtin_amdgcn_s_barrier();
      __builtin_amdgcn_s_setprio(1);
      #pragma unroll
      for (int mi = 4; mi < 8; ++mi)
        #pragma unroll
        for (int ni = 0; ni < 4; ++ni)
          acc[mi][ni] = __builtin_amdgcn_mfma_f32_16x16x32_bf16(
              __builtin_bit_cast(bf16x8, af[mi]), __builtin_bit_cast(bf16x8, bfr[ni]),
              acc[mi][ni], 0, 0, 0);
      __builtin_amdgcn_s_setprio(0);
      // counted drains (audited, r7): A-phase needs t.kh1; B-phase needs (t+1).kh0
      if (kh == 0) {
        if (t < GNT - 1) asm volatile("s_waitcnt vmcnt(8)" ::: "memory");
        else             asm volatile("s_waitcnt vmcnt(0)" ::: "memory");
      } else {
        if (t < GNT - 2)      asm volatile("s_waitcnt vmcnt(8)" ::: "memory");
        else if (t == GNT - 2) asm volatile("s_waitcnt vmcnt(4)" ::: "memory");
      }
      __builtin_amdgcn_s_barrier();
    }
  }

  // epilogue: bias + NT store
  #pragma unroll
  for (int ni = 0; ni < 4; ++ni) {
    const int col = tn + wc * 64 + ni * 16 + l15;
    const float bb = b1[col];
    #pragma unroll
    for (int mi = 0; mi < 8; ++mi)
      #pragma unroll
      for (int reg = 0; reg < 4; ++reg) {
        const int row = tm + wr * 128 + mi * 16 + hi * 4 + reg;
        __builtin_nontemporal_store(f2bf(acc[mi][ni][reg] + bb),
                                    H + (size_t)row * NH + col);
      }
  }
}

// ---------------- self-pred gather: branch-free unrolled ----------------
template <int KM>
__device__ __forceinline__ void gather_chunk(
    const unsigned short* __restrict__ T, const int* idxrow,
    int oo, int bbv, float v[8]) {
  #pragma unroll
  for (int kc = 0; kc < KM; ++kc) {
    int c = idxrow[kc];
    float m = (c >= 0 && kc <= bbv) ? 1.f : 0.f;
    int cc = c < 0 ? 0 : (c >= CS ? CS - 1 : c);
    int4v tv = *(const int4v*)(T + (size_t)(kc * CS + cc) * LSR + oo);
    const unsigned short* ts = (const unsigned short*)&tv;
    #pragma unroll
    for (int e = 0; e < 8; ++e) v[e] = fmaf(m, bf2f(ts[e]), v[e]);
  }
}

// grid = dim3(3, SA_NBLK): x = 2048-col stripe (compile-time gather depth),
// y = 32-row block. 1536 blocks -> 6/CU. One 8-col chunk per thread per row.
__global__ __launch_bounds__(256) void k_selfadd(
    unsigned short* __restrict__ H,        // [NROW][NH] bf16, in-place
    const unsigned short* __restrict__ T,  // [LSC][LSR] bf16 (linear_self^T)
    const int* __restrict__ ci,
    float* __restrict__ partials) {        // [2][SA_NBLK][NH]
  __shared__ int idxs[SA_ROWS][NCB];
  const int tid = threadIdx.x;
  const int row0 = blockIdx.y * SA_ROWS;
  const int sx = blockIdx.x;               // 0..2, block-uniform
  for (int i = tid; i < SA_ROWS * NCB; i += 256)
    idxs[i >> 4][i & 15] = ci[(size_t)(row0 + (i >> 4)) * NCB + (i & 15)];
  __syncthreads();

  const int col0 = sx * 2048 + tid * 8;
  const int o = col0 - HD;
  const int oo = o < 0 ? 0 : o;
  const int bb = o < 0 ? -1 : o / HD;

  float cs[8] = {0}, cq[8] = {0};

  for (int rr = 0; rr < SA_ROWS; ++rr) {
    const size_t ro = (size_t)(row0 + rr) * NH;
    int4v hv = __builtin_nontemporal_load((const int4v*)(H + ro + col0));
    const unsigned short* hs = (const unsigned short*)&hv;
    float v[8];
    #pragma unroll
    for (int e = 0; e < 8; ++e) v[e] = bf2f(hs[e]);
    switch (sx) {  // block-uniform branch, compile-time gather depth
      case 0: gather_chunk<5>(T, idxs[rr], oo, bb, v); break;
      case 1: gather_chunk<10>(T, idxs[rr], oo, bb, v); break;
      default: gather_chunk<15>(T, idxs[rr], oo, bb, v); break;
    }
    unsigned short os[8];
    #pragma unroll
    for (int e = 0; e < 8; ++e) {
      float x = fmaxf(v[e], 0.f);
      unsigned short hb = f2bf(x);
      os[e] = hb;
      float xr = bf2f(hb);
      cs[e] += xr;
      cq[e] += xr * xr;
    }
    // NT store: keep T resident in L2/L3; passc re-fetches H from HBM anyway
    __builtin_nontemporal_store(*(const int4v*)os, (int4v*)(H + ro + col0));
  }

  float* Ps = partials + (size_t)blockIdx.y * NH + col0;
  float* Pq = partials + (size_t)(SA_NBLK + blockIdx.y) * NH + col0;
  float4 a = {cs[0], cs[1], cs[2], cs[3]};
  float4 b4 = {cs[4], cs[5], cs[6], cs[7]};
  *(float4*)Ps = a; *(float4*)(Ps + 4) = b4;
  float4 c4 = {cq[0], cq[1], cq[2], cq[3]};
  float4 d4 = {cq[4], cq[5], cq[6], cq[7]};
  *(float4*)Pq = c4; *(float4*)(Pq + 4) = d4;
}

// ---------------- reduce partials -> colsum/colsq ----------------
// grid dim3(NH/256, 8)
__global__ void k_red(const float* __restrict__ partials,
                      float* __restrict__ colsum, float* __restrict__ colsq) {
  int j = blockIdx.x * 256 + threadIdx.x;
  const float* Ps = partials;
  const float* Pq = partials + (size_t)SA_NBLK * NH;
  float s = 0.f, q = 0.f;
  const int b0 = blockIdx.y * (SA_NBLK / 8), b1 = b0 + SA_NBLK / 8;
  for (int by = b0; by < b1; ++by) {
    s += Ps[(size_t)by * NH + j];
    q += Pq[(size_t)by * NH + j];
  }
  atomicAdd(colsum + j, s);
  atomicAdd(colsq + j, q);
}

// ---------------- BN params ----------------
__global__ void k_bn(const float* __restrict__ colsum, const float* __restrict__ colsq,
                     const float* __restrict__ gamma, const float* __restrict__ beta,
                     float* __restrict__ scale, float* __restrict__ shift) {
  int j = blockIdx.x * 256 + threadIdx.x;
  if (j >= NH) return;
  float mean = colsum[j] * (1.f / NROW);
  float var = colsq[j] * (1.f / NROW) - mean * mean;
  var = fmaxf(var, 0.f);
  float rs = rsqrtf(var + 1e-5f);
  float g = gamma[j] * rs;
  scale[j] = g;
  shift[j] = beta[j] - mean * g;
}

// ---------------- fold BN into linear2/bias2 ----------------
__global__ __launch_bounds__(128) void k_fold(
    const float* __restrict__ L2, const float* __restrict__ bias2,
    const float* __restrict__ scale, const float* __restrict__ shift,
    unsigned short* __restrict__ L2b, float* __restrict__ bias2p) {
  __shared__ float red[2];
  int kc = blockIdx.x;        // k*256 + c
  int k = kc >> 8;
  size_t off = (size_t)kc * HD;
  float a = 0.f;
  for (int h = threadIdx.x; h < HD; h += 128) {
    float wv = L2[off + h];
    int jh = k * HD + h;
    L2b[off + h] = f2bf(wv * scale[jh]);
    a += wv * shift[jh];
  }
  #pragma unroll
  for (int m = 1; m < 64; m <<= 1) a += __shfl_xor(a, m);
  if ((threadIdx.x & 63) == 0) red[threadIdx.x >> 6] = a;
  __syncthreads();
  if (threadIdx.x == 0) bias2p[kc] = bias2[kc] + red[0] + red[1];
}

// ---------------- pass C: logits GEMM + log-softmax + target gather ----------------
// grid dim3(256,16); XCD swizzle: each XCD owns 2 codebooks (L2b panels L2-resident)
__global__ __launch_bounds__(256, 2) void k_passc(
    const unsigned short* __restrict__ H,     // [NROW][NH] bf16
    const unsigned short* __restrict__ L2b,   // [NCB][CS][HD] bf16 (BN-folded)
    const float* __restrict__ bias2p,         // [NCB][CS]
    const int* __restrict__ ci,
    float* __restrict__ out) {
  __shared__ char smem[64 * 260 * 4];
  __shared__ float red[4];
  int4* As = (int4*)smem;              // [kg 0..3][row 0..63]
  int4* Bs = (int4*)(smem + 4096);     // [kg 0..3][col 0..255]
  float* lg = (float*)smem;            // [64][260]

  const int tid = threadIdx.x, lane = tid & 63, w = tid >> 6;
  const int bidf = blockIdx.y * gridDim.x + blockIdx.x;  // 0..4095
  const int xcd = bidf & 7, p = bidf >> 3;               // p in [0,512)
  const int k = xcd * 2 + (p & 1);
  const int tm = (p >> 1) * 64;
  const int r = lane & 15, kg = lane >> 4;

  f32x4 acc[4][4] = {};
  for (int kk = 0; kk < HD / 32; ++kk) {  // 12 steps
    const int k0 = kk * 32;
    {
      int s = w * 64 + lane;
      int srow = s & 63, skg = s >> 6;
      gload16(As + w * 64, H + (size_t)(tm + srow) * NH + k * HD + k0 + skg * 8);
    }
    #pragma unroll
    for (int i = 0; i < 4; ++i) {
      int s = i * 256 + w * 64 + lane;
      int srow = s & 255, skg = s >> 8;
      gload16(Bs + i * 256 + w * 64, L2b + (size_t)(k * CS + srow) * HD + k0 + skg * 8);
    }
    asm volatile("s_waitcnt vmcnt(0)" ::: "memory");
    __syncthreads();
    int4 af[4], bfr[4];
    #pragma unroll
    for (int mi = 0; mi < 4; ++mi) af[mi] = As[kg * 64 + mi * 16 + r];
    #pragma unroll
    for (int ni = 0; ni < 4; ++ni) bfr[ni] = Bs[kg * 256 + w * 64 + ni * 16 + r];
    #pragma unroll
    for (int mi = 0; mi < 4; ++mi)
      #pragma unroll
      for (int ni = 0; ni < 4; ++ni)
        acc[mi][ni] = __builtin_amdgcn_mfma_f32_16x16x32_bf16(
            __builtin_bit_cast(bf16x8, af[mi]), __builtin_bit_cast(bf16x8, bfr[ni]),
            acc[mi][ni], 0, 0, 0);
    __syncthreads();
  }

  const int lr0 = (lane >> 4) * 4;
  #pragma unroll
  for (int mi = 0; mi < 4; ++mi)
    #pragma unroll
    for (int ni = 0; ni < 4; ++ni) {
      int col = w * 64 + ni * 16 + r;
      float bb = bias2p[k * CS + col];
      #pragma unroll
      for (int reg = 0; reg < 4; ++reg) {
        int row = mi * 16 + lr0 + reg;
        lg[row * 260 + col] = acc[mi][ni][reg] + bb;
      }
    }
  __syncthreads();

  int row = tid >> 2, part = tid & 3;
  const float4* rp = (const float4*)(lg + row * 260 + part * 64);
  float m = -1e30f;
  #pragma unroll
  for (int i = 0; i < 16; ++i) {
    float4 v = rp[i];
    m = fmaxf(m, fmaxf(fmaxf(v.x, v.y), fmaxf(v.z, v.w)));
  }
  m = fmaxf(m, __shfl_xor(m, 1));
  m = fmaxf(m, __shfl_xor(m, 2));
  float s = 0.f;
  #pragma unroll
  for (int i = 0; i < 16; ++i) {
    float4 v = rp[i];
    s += __expf(v.x - m) + __expf(v.y - m) + __expf(v.z - m) + __expf(v.w - m);
  }
  s += __shfl_xor(s, 1);
  s += __shfl_xor(s, 2);
  float contrib = 0.f;
  if (part == 0) {
    float lse = m + __logf(s);
    int c = ci[(size_t)(tm + row) * NCB + k];
    if (c >= 0) {
      c = c < CS ? c : CS - 1;
      contrib = lg[row * 260 + c] - lse;
    }
  }
  #pragma unroll
  for (int msk = 1; msk < 64; msk <<= 1) contrib += __shfl_xor(contrib, msk);
  if (lane == 0) red[w] = contrib;
  __syncthreads();
  if (tid == 0) atomicAdd(out, red[0] + red[1] + red[2] + red[3]);
}

extern "C" void kernel_launch(void* const* d_in, const int* in_sizes, int n_in,
                              void* d_out, int out_size, void* d_ws, size_t ws_size,
                              hipStream_t stream) {
  const float* predictor = (const float*)d_in[0];
  const int* cbidx       = (const int*)d_in[1];
  const float* W1        = (const float*)d_in[2];
  const float* b1        = (const float*)d_in[3];
  const float* lself     = (const float*)d_in[4];
  const float* gamma     = (const float*)d_in[5];
  const float* beta      = (const float*)d_in[6];
  const float* L2        = (const float*)d_in[7];
  const float* bias2     = (const float*)d_in[8];
  float* out = (float*)d_out;

  char* ws = (char*)d_ws;
  size_t off = 0;
  auto alloc = [&](size_t bytes) {
    char* p = ws + off;
    off += (bytes + 255) & ~(size_t)255;
    return p;
  };
  unsigned short* predB  = (unsigned short*)alloc((size_t)NROW * PD * 2);
  unsigned short* W1B    = (unsigned short*)alloc((size_t)NH * PD * 2);
  unsigned short* T      = (unsigned short*)alloc((size_t)LSC * LSR * 2);
  unsigned short* Hb     = (unsigned short*)alloc((size_t)NROW * NH * 2);
  unsigned short* L2b    = (unsigned short*)alloc((size_t)NCB * CS * HD * 2);
  float* partials = (float*)alloc((size_t)2 * SA_NBLK * NH * 4);
  float* colsum = (float*)alloc(NH * 4);
  float* colsq  = (float*)alloc(NH * 4);
  float* scale  = (float*)alloc(NH * 4);
  float* shift  = (float*)alloc(NH * 4);
  float* bias2p = (float*)alloc(NCB * CS * 4);

  hipMemsetAsync(d_out, 0, 2 * sizeof(float), stream);
  hipMemsetAsync(colsum, 0, NH * 4, stream);
  hipMemsetAsync(colsq, 0, NH * 4, stream);

  k_f2b<<<2048, 256, 0, stream>>>(predictor, predB, NROW * PD / 4);
  k_f2b<<<2048, 256, 0, stream>>>(W1, W1B, NH * PD / 4);
  k_transpose<<<dim3(LSC / 32, LSR / 32), 256, 0, stream>>>(lself, T);
  k_count<<<NROW / 256, 256, 0, stream>>>(cbidx, out);
  k_gemm1<<<(NROW / 256) * (NH / 256), 512, 0, stream>>>(predB, W1B, b1, Hb);
  k_selfadd<<<dim3(3, SA_NBLK), 256, 0, stream>>>(Hb, T, cbidx, partials);
  k_red<<<dim3(NH / 256, 8), 256, 0, stream>>>(partials, colsum, colsq);
  k_bn<<<NH / 256, 256, 0, stream>>>(colsum, colsq, gamma, beta, scale, shift);
  k_fold<<<NCB * CS, 128, 0, stream>>>(L2, bias2, scale, shift, L2b, bias2p);
  k_passc<<<dim3(NROW / 64, NCB), 256, 0, stream>>>(Hb, L2b, bias2p, cbidx, out);
}

// Round 10
// 1156.099 us; speedup vs baseline: 1.0710x; 1.0710x over previous
//
#include <hip/hip_runtime.h>
#include <hip/hip_bf16.h>

#define NCB 16
#define CS 256
#define HD 384
#define PD 2048
#define NROW 16384
#define NH 6144      // NCB*HD
#define LSR 5760     // (NCB-1)*HD  rows of linear_self
#define LSC 3840     // (NCB-1)*CS  cols of linear_self
#define SA_ROWS 32
#define SA_NBLK (NROW / SA_ROWS)   // 512
#define GNT (PD / 64)              // 32 K-tiles for gemm1

typedef __bf16 bf16x8 __attribute__((ext_vector_type(8)));
typedef float f32x4 __attribute__((ext_vector_type(4)));
typedef int int4v __attribute__((ext_vector_type(4)));

__device__ __forceinline__ unsigned short f2bf(float f) {
  unsigned u = __builtin_bit_cast(unsigned, f);
  u = (u + 0x7fffu + ((u >> 16) & 1u)) >> 16;
  return (unsigned short)u;
}
__device__ __forceinline__ float bf2f(unsigned short h) {
  unsigned u = ((unsigned)h) << 16;
  return __builtin_bit_cast(float, u);
}

__device__ __forceinline__ void gload16(void* lds, const void* g) {
  __builtin_amdgcn_global_load_lds(
      (const __attribute__((address_space(1))) unsigned int*)g,
      (__attribute__((address_space(3))) unsigned int*)lds, 16, 0, 0);
}

// ---------------- fp32 -> bf16 conversion ----------------
__global__ void k_f2b(const float* __restrict__ in, unsigned short* __restrict__ out, int n4) {
  for (int i = blockIdx.x * 256 + threadIdx.x; i < n4; i += gridDim.x * 256) {
    float4 v = ((const float4*)in)[i];
    ushort4 o;
    o.x = f2bf(v.x); o.y = f2bf(v.y); o.z = f2bf(v.z); o.w = f2bf(v.w);
    ((ushort4*)out)[i] = o;
  }
}

// ---------------- transpose linear_self (5760x3840 f32) -> T (3840x5760 bf16) ----------------
__global__ __launch_bounds__(256) void k_transpose(const float* __restrict__ LS,
                                                   unsigned short* __restrict__ T) {
  __shared__ float tile[32][33];
  int tx = threadIdx.x & 31, ty = threadIdx.x >> 5;
  int c0 = blockIdx.x * 32;  // col of LS = row of T
  int r0 = blockIdx.y * 32;  // row of LS = col of T
  for (int i = ty; i < 32; i += 8)
    tile[i][tx] = LS[(size_t)(r0 + i) * LSC + c0 + tx];
  __syncthreads();
  for (int i = ty; i < 32; i += 8)
    T[(size_t)(c0 + i) * LSR + r0 + tx] = f2bf(tile[tx][i]);
}

// ---------------- count valid[:,0] ----------------
__global__ void k_count(const int* __restrict__ ci, float* __restrict__ out) {
  int n = blockIdx.x * 256 + threadIdx.x;
  float v = (n < NROW && ci[(size_t)n * NCB] >= 0) ? 1.f : 0.f;
  #pragma unroll
  for (int m = 1; m < 64; m <<= 1) v += __shfl_xor(v, m);
  if ((threadIdx.x & 63) == 0) atomicAdd(out + 1, v);
}

// ---------------- GEMM1: 256x256 tile, BK=64 (2 k-halves), 8 waves, counted vmcnt ----------------
// r7 verbatim (577 us proven): 2 barriers per 32-MFMA window, counted vmcnt(8).
__global__ __launch_bounds__(512, 2) void k_gemm1(
    const unsigned short* __restrict__ A,   // predictor bf16 [NROW][PD]
    const unsigned short* __restrict__ B,   // W1 bf16 [NH][PD]
    const float* __restrict__ b1,
    unsigned short* __restrict__ H) {       // out [NROW][NH]
  __shared__ int4 Al[2][2][1024];   // 64 KB
  __shared__ int4 Bl[2][2][1024];   // 64 KB

  const int tid = threadIdx.x;
  const int lane = tid & 63;
  const int w = tid >> 6;             // 0..7
  const int wr = w >> 2, wc = w & 3;  // wave grid 2(M) x 4(N)
  const int l15 = lane & 15, hi = lane >> 4;
  const int w64 = tid & ~63;

  // XCD swizzle: grid 1536 = 64 mt x 24 nt; each XCD owns 3 nt (3MB B -> L2)
  const int bid = blockIdx.x;
  const int xcd = bid & 7, p = bid >> 3;   // p in [0,192)
  const int nt = xcd * 3 + p % 3;
  const int mt = p / 3;
  const int tm = mt * 256, tn = nt * 256;

  f32x4 acc[8][4] = {};

  auto STAGE = [&](int buf, int t, int kh) {
    const int kb = t * 64 + kh * 32;
    #pragma unroll
    for (int g = 0; g < 2; ++g) {
      const int slot = g * 512 + tid;
      const int row = slot >> 2;                       // 0..255
      const int lc = (slot & 3) ^ ((row >> 1) & 3);    // inverse-swizzled source col
      gload16(&Al[buf][kh][g * 512 + w64], A + (size_t)(tm + row) * PD + kb + lc * 8);
      gload16(&Bl[buf][kh][g * 512 + w64], B + (size_t)(tn + row) * PD + kb + lc * 8);
    }
  };

  // prologue: t0.kh0, t0.kh1, t1.kh0 -> 12 loads; wait oldest 4 (t0.kh0)
  STAGE(0, 0, 0);
  STAGE(0, 0, 1);
  STAGE(1, 1, 0);
  asm volatile("s_waitcnt vmcnt(8)" ::: "memory");
  __builtin_amdgcn_s_barrier();

  for (int t = 0; t < GNT; ++t) {
    const int buf = t & 1;
    #pragma unroll
    for (int kh = 0; kh < 2; ++kh) {
      // frag reads (swizzled)
      int4 af[8], bfr[4];
      #pragma unroll
      for (int mi = 0; mi < 8; ++mi) {
        const int row = wr * 128 + mi * 16 + l15;
        const int pc = hi ^ ((row >> 1) & 3);
        af[mi] = Al[buf][kh][row * 4 + pc];
      }
      #pragma unroll
      for (int ni = 0; ni < 4; ++ni) {
        const int row = wc * 64 + ni * 16 + l15;
        const int pc = hi ^ ((row >> 1) & 3);
        bfr[ni] = Bl[buf][kh][row * 4 + pc];
      }
      // stage (regions race-safe, r7 audit)
      if (kh == 0) {
        if (t + 1 < GNT) STAGE(buf ^ 1, t + 1, 1);
      } else {
        if (t + 2 < GNT) STAGE(buf, t + 2, 0);
      }
      __builtin_amdgcn_s_barrier();
      __builtin_amdgcn_s_setprio(1);
      #pragma unroll
      for (int mi = 0; mi < 8; ++mi)
        #pragma unroll
        for (int ni = 0; ni < 4; ++ni)
          acc[mi][ni] = __builtin_amdgcn_mfma_f32_16x16x32_bf16(
              __builtin_bit_cast(bf16x8, af[mi]), __builtin_bit_cast(bf16x8, bfr[ni]),
              acc[mi][ni], 0, 0, 0);
      __builtin_amdgcn_s_setprio(0);
      // counted drains (audited): A-phase needs t.kh1; B-phase needs (t+1).kh0
      if (kh == 0) {
        if (t < GNT - 1) asm volatile("s_waitcnt vmcnt(8)" ::: "memory");
        else             asm volatile("s_waitcnt vmcnt(0)" ::: "memory");
      } else {
        if (t < GNT - 2)      asm volatile("s_waitcnt vmcnt(8)" ::: "memory");
        else if (t == GNT - 2) asm volatile("s_waitcnt vmcnt(4)" ::: "memory");
      }
      __builtin_amdgcn_s_barrier();
    }
  }

  // epilogue: bias + NT store
  #pragma unroll
  for (int ni = 0; ni < 4; ++ni) {
    const int col = tn + wc * 64 + ni * 16 + l15;
    const float bb = b1[col];
    #pragma unroll
    for (int mi = 0; mi < 8; ++mi)
      #pragma unroll
      for (int reg = 0; reg < 4; ++reg) {
        const int row = tm + wr * 128 + mi * 16 + hi * 4 + reg;
        __builtin_nontemporal_store(f2bf(acc[mi][ni][reg] + bb),
                                    H + (size_t)row * NH + col);
      }
  }
}

// ---------------- self-pred gather: branch-free unrolled ----------------
template <int KM>
__device__ __forceinline__ void gather_chunk(
    const unsigned short* __restrict__ T, const int* idxrow,
    int oo, int bbv, float v[8]) {
  #pragma unroll
  for (int kc = 0; kc < KM; ++kc) {
    int c = idxrow[kc];
    float m = (c >= 0 && kc <= bbv) ? 1.f : 0.f;
    int cc = c < 0 ? 0 : (c >= CS ? CS - 1 : c);
    int4v tv = *(const int4v*)(T + (size_t)(kc * CS + cc) * LSR + oo);
    const unsigned short* ts = (const unsigned short*)&tv;
    #pragma unroll
    for (int e = 0; e < 8; ++e) v[e] = fmaf(m, bf2f(ts[e]), v[e]);
  }
}

// grid = dim3(3, SA_NBLK): x = 2048-col stripe (compile-time gather depth),
// y = 32-row block. 1536 blocks -> 6/CU. One 8-col chunk per thread per row.
__global__ __launch_bounds__(256) void k_selfadd(
    unsigned short* __restrict__ H,        // [NROW][NH] bf16, in-place
    const unsigned short* __restrict__ T,  // [LSC][LSR] bf16 (linear_self^T)
    const int* __restrict__ ci,
    float* __restrict__ partials) {        // [2][SA_NBLK][NH]
  __shared__ int idxs[SA_ROWS][NCB];
  const int tid = threadIdx.x;
  const int row0 = blockIdx.y * SA_ROWS;
  const int sx = blockIdx.x;               // 0..2, block-uniform
  for (int i = tid; i < SA_ROWS * NCB; i += 256)
    idxs[i >> 4][i & 15] = ci[(size_t)(row0 + (i >> 4)) * NCB + (i & 15)];
  __syncthreads();

  const int col0 = sx * 2048 + tid * 8;
  const int o = col0 - HD;
  const int oo = o < 0 ? 0 : o;
  const int bb = o < 0 ? -1 : o / HD;

  float cs[8] = {0}, cq[8] = {0};

  for (int rr = 0; rr < SA_ROWS; ++rr) {
    const size_t ro = (size_t)(row0 + rr) * NH;
    int4v hv = __builtin_nontemporal_load((const int4v*)(H + ro + col0));
    const unsigned short* hs = (const unsigned short*)&hv;
    float v[8];
    #pragma unroll
    for (int e = 0; e < 8; ++e) v[e] = bf2f(hs[e]);
    switch (sx) {  // block-uniform branch, compile-time gather depth
      case 0: gather_chunk<5>(T, idxs[rr], oo, bb, v); break;
      case 1: gather_chunk<10>(T, idxs[rr], oo, bb, v); break;
      default: gather_chunk<15>(T, idxs[rr], oo, bb, v); break;
    }
    unsigned short os[8];
    #pragma unroll
    for (int e = 0; e < 8; ++e) {
      float x = fmaxf(v[e], 0.f);
      unsigned short hb = f2bf(x);
      os[e] = hb;
      float xr = bf2f(hb);
      cs[e] += xr;
      cq[e] += xr * xr;
    }
    // NT store: keep T resident in L2/L3; passc re-fetches H from HBM anyway
    __builtin_nontemporal_store(*(const int4v*)os, (int4v*)(H + ro + col0));
  }

  float* Ps = partials + (size_t)blockIdx.y * NH + col0;
  float* Pq = partials + (size_t)(SA_NBLK + blockIdx.y) * NH + col0;
  float4 a = {cs[0], cs[1], cs[2], cs[3]};
  float4 b4 = {cs[4], cs[5], cs[6], cs[7]};
  *(float4*)Ps = a; *(float4*)(Ps + 4) = b4;
  float4 c4 = {cq[0], cq[1], cq[2], cq[3]};
  float4 d4 = {cq[4], cq[5], cq[6], cq[7]};
  *(float4*)Pq = c4; *(float4*)(Pq + 4) = d4;
}

// ---------------- reduce partials -> colsum/colsq ----------------
// grid dim3(NH/256, 8)
__global__ void k_red(const float* __restrict__ partials,
                      float* __restrict__ colsum, float* __restrict__ colsq) {
  int j = blockIdx.x * 256 + threadIdx.x;
  const float* Ps = partials;
  const float* Pq = partials + (size_t)SA_NBLK * NH;
  float s = 0.f, q = 0.f;
  const int b0 = blockIdx.y * (SA_NBLK / 8), b1 = b0 + SA_NBLK / 8;
  for (int by = b0; by < b1; ++by) {
    s += Ps[(size_t)by * NH + j];
    q += Pq[(size_t)by * NH + j];
  }
  atomicAdd(colsum + j, s);
  atomicAdd(colsq + j, q);
}

// ---------------- BN params ----------------
__global__ void k_bn(const float* __restrict__ colsum, const float* __restrict__ colsq,
                     const float* __restrict__ gamma, const float* __restrict__ beta,
                     float* __restrict__ scale, float* __restrict__ shift) {
  int j = blockIdx.x * 256 + threadIdx.x;
  if (j >= NH) return;
  float mean = colsum[j] * (1.f / NROW);
  float var = colsq[j] * (1.f / NROW) - mean * mean;
  var = fmaxf(var, 0.f);
  float rs = rsqrtf(var + 1e-5f);
  float g = gamma[j] * rs;
  scale[j] = g;
  shift[j] = beta[j] - mean * g;
}

// ---------------- fold BN into linear2/bias2 ----------------
__global__ __launch_bounds__(128) void k_fold(
    const float* __restrict__ L2, const float* __restrict__ bias2,
    const float* __restrict__ scale, const float* __restrict__ shift,
    unsigned short* __restrict__ L2b, float* __restrict__ bias2p) {
  __shared__ float red[2];
  int kc = blockIdx.x;        // k*256 + c
  int k = kc >> 8;
  size_t off = (size_t)kc * HD;
  float a = 0.f;
  for (int h = threadIdx.x; h < HD; h += 128) {
    float wv = L2[off + h];
    int jh = k * HD + h;
    L2b[off + h] = f2bf(wv * scale[jh]);
    a += wv * shift[jh];
  }
  #pragma unroll
  for (int m = 1; m < 64; m <<= 1) a += __shfl_xor(a, m);
  if ((threadIdx.x & 63) == 0) red[threadIdx.x >> 6] = a;
  __syncthreads();
  if (threadIdx.x == 0) bias2p[kc] = bias2[kc] + red[0] + red[1];
}

// ---------------- pass C: logits GEMM + log-softmax + target gather ----------------
// grid dim3(256,16); XCD swizzle (2 codebooks/XCD -> L2b L2-resident);
// T3-minimum double-buffer: STAGE(next) issued before frag-read/MFMA(cur),
// single drain+barrier per K-step. LDS 66.5KB -> 2 blocks/CU overlap.
__global__ __launch_bounds__(256, 2) void k_passc(
    const unsigned short* __restrict__ H,     // [NROW][NH] bf16
    const unsigned short* __restrict__ L2b,   // [NCB][CS][HD] bf16 (BN-folded)
    const float* __restrict__ bias2p,         // [NCB][CS]
    const int* __restrict__ ci,
    float* __restrict__ out) {
  __shared__ char smem[64 * 260 * 4];  // 66560B; staging dbuf (40KB) aliased under lg
  __shared__ float red[4];
  float* lg = (float*)smem;            // [64][260]

  const int tid = threadIdx.x, lane = tid & 63, w = tid >> 6;
  const int bidf = blockIdx.y * gridDim.x + blockIdx.x;  // 0..4095
  const int xcd = bidf & 7, p = bidf >> 3;               // p in [0,512)
  const int k = xcd * 2 + (p & 1);
  const int tm = (p >> 1) * 64;
  const int r = lane & 15, kg = lane >> 4;

  auto Asb = [&](int buf) { return (int4*)(smem + buf * 20480); };          // 4KB
  auto Bsb = [&](int buf) { return (int4*)(smem + buf * 20480 + 4096); };   // 16KB

  const int s0r = (w * 64 + lane) & 63, s0g = (w * 64 + lane) >> 6;
  auto STAGE = [&](int buf, int kk) {
    const int k0 = kk * 32;
    gload16(Asb(buf) + w * 64, H + (size_t)(tm + s0r) * NH + k * HD + k0 + s0g * 8);
    #pragma unroll
    for (int i = 0; i < 4; ++i) {
      int s = i * 256 + w * 64 + lane;
      int srow = s & 255, skg = s >> 8;
      gload16(Bsb(buf) + i * 256 + w * 64,
              L2b + (size_t)(k * CS + srow) * HD + k0 + skg * 8);
    }
  };

  f32x4 acc[4][4] = {};
  int buf = 0;
  STAGE(0, 0);
  asm volatile("s_waitcnt vmcnt(0)" ::: "memory");
  __syncthreads();

  for (int kk = 0; kk < HD / 32; ++kk) {  // 12 steps
    if (kk + 1 < HD / 32) STAGE(buf ^ 1, kk + 1);   // 5 loads in flight during compute
    int4 af[4], bfr[4];
    #pragma unroll
    for (int mi = 0; mi < 4; ++mi) af[mi] = Asb(buf)[kg * 64 + mi * 16 + r];
    #pragma unroll
    for (int ni = 0; ni < 4; ++ni) bfr[ni] = Bsb(buf)[kg * 256 + w * 64 + ni * 16 + r];
    #pragma unroll
    for (int mi = 0; mi < 4; ++mi)
      #pragma unroll
      for (int ni = 0; ni < 4; ++ni)
        acc[mi][ni] = __builtin_amdgcn_mfma_f32_16x16x32_bf16(
            __builtin_bit_cast(bf16x8, af[mi]), __builtin_bit_cast(bf16x8, bfr[ni]),
            acc[mi][ni], 0, 0, 0);
    __syncthreads();   // drains vmcnt (staged loads had full MFMA window to land)
    buf ^= 1;
  }

  const int lr0 = (lane >> 4) * 4;
  #pragma unroll
  for (int mi = 0; mi < 4; ++mi)
    #pragma unroll
    for (int ni = 0; ni < 4; ++ni) {
      int col = w * 64 + ni * 16 + r;
      float bb = bias2p[k * CS + col];
      #pragma unroll
      for (int reg = 0; reg < 4; ++reg) {
        int row = mi * 16 + lr0 + reg;
        lg[row * 260 + col] = acc[mi][ni][reg] + bb;
      }
    }
  __syncthreads();

  int row = tid >> 2, part = tid & 3;
  const float4* rp = (const float4*)(lg + row * 260 + part * 64);
  float m = -1e30f;
  #pragma unroll
  for (int i = 0; i < 16; ++i) {
    float4 v = rp[i];
    m = fmaxf(m, fmaxf(fmaxf(v.x, v.y), fmaxf(v.z, v.w)));
  }
  m = fmaxf(m, __shfl_xor(m, 1));
  m = fmaxf(m, __shfl_xor(m, 2));
  float s = 0.f;
  #pragma unroll
  for (int i = 0; i < 16; ++i) {
    float4 v = rp[i];
    s += __expf(v.x - m) + __expf(v.y - m) + __expf(v.z - m) + __expf(v.w - m);
  }
  s += __shfl_xor(s, 1);
  s += __shfl_xor(s, 2);
  float contrib = 0.f;
  if (part == 0) {
    float lse = m + __logf(s);
    int c = ci[(size_t)(tm + row) * NCB + k];
    if (c >= 0) {
      c = c < CS ? c : CS - 1;
      contrib = lg[row * 260 + c] - lse;
    }
  }
  #pragma unroll
  for (int msk = 1; msk < 64; msk <<= 1) contrib += __shfl_xor(contrib, msk);
  if (lane == 0) red[w] = contrib;
  __syncthreads();
  if (tid == 0) atomicAdd(out, red[0] + red[1] + red[2] + red[3]);
}

extern "C" void kernel_launch(void* const* d_in, const int* in_sizes, int n_in,
                              void* d_out, int out_size, void* d_ws, size_t ws_size,
                              hipStream_t stream) {
  const float* predictor = (const float*)d_in[0];
  const int* cbidx       = (const int*)d_in[1];
  const float* W1        = (const float*)d_in[2];
  const float* b1        = (const float*)d_in[3];
  const float* lself     = (const float*)d_in[4];
  const float* gamma     = (const float*)d_in[5];
  const float* beta      = (const float*)d_in[6];
  const float* L2        = (const float*)d_in[7];
  const float* bias2     = (const float*)d_in[8];
  float* out = (float*)d_out;

  char* ws = (char*)d_ws;
  size_t off = 0;
  auto alloc = [&](size_t bytes) {
    char* p = ws + off;
    off += (bytes + 255) & ~(size_t)255;
    return p;
  };
  unsigned short* predB  = (unsigned short*)alloc((size_t)NROW * PD * 2);
  unsigned short* W1B    = (unsigned short*)alloc((size_t)NH * PD * 2);
  unsigned short* T      = (unsigned short*)alloc((size_t)LSC * LSR * 2);
  unsigned short* Hb     = (unsigned short*)alloc((size_t)NROW * NH * 2);
  unsigned short* L2b    = (unsigned short*)alloc((size_t)NCB * CS * HD * 2);
  float* partials = (float*)alloc((size_t)2 * SA_NBLK * NH * 4);
  float* colsum = (float*)alloc(NH * 4);
  float* colsq  = (float*)alloc(NH * 4);
  float* scale  = (float*)alloc(NH * 4);
  float* shift  = (float*)alloc(NH * 4);
  float* bias2p = (float*)alloc(NCB * CS * 4);

  hipMemsetAsync(d_out, 0, 2 * sizeof(float), stream);
  hipMemsetAsync(colsum, 0, NH * 4, stream);
  hipMemsetAsync(colsq, 0, NH * 4, stream);

  k_f2b<<<2048, 256, 0, stream>>>(predictor, predB, NROW * PD / 4);
  k_f2b<<<2048, 256, 0, stream>>>(W1, W1B, NH * PD / 4);
  k_transpose<<<dim3(LSC / 32, LSR / 32), 256, 0, stream>>>(lself, T);
  k_count<<<NROW / 256, 256, 0, stream>>>(cbidx, out);
  k_gemm1<<<(NROW / 256) * (NH / 256), 512, 0, stream>>>(predB, W1B, b1, Hb);
  k_selfadd<<<dim3(3, SA_NBLK), 256, 0, stream>>>(Hb, T, cbidx, partials);
  k_red<<<dim3(NH / 256, 8), 256, 0, stream>>>(partials, colsum, colsq);
  k_bn<<<NH / 256, 256, 0, stream>>>(colsum, colsq, gamma, beta, scale, shift);
  k_fold<<<NCB * CS, 128, 0, stream>>>(L2, bias2, scale, shift, L2b, bias2p);
  k_passc<<<dim3(NROW / 64, NCB), 256, 0, stream>>>(Hb, L2b, bias2p, cbidx, out);
}

// Round 11
// 1114.500 us; speedup vs baseline: 1.1110x; 1.0373x over previous
//
#include <hip/hip_runtime.h>
#include <hip/hip_bf16.h>

#define NCB 16
#define CS 256
#define HD 384
#define PD 2048
#define NROW 16384
#define NH 6144      // NCB*HD
#define LSR 5760     // (NCB-1)*HD  rows of linear_self
#define LSC 3840     // (NCB-1)*CS  cols of linear_self
#define SA_ROWS 32
#define SA_NBLK (NROW / SA_ROWS)   // 512
#define GNT (PD / 64)              // 32 K-tiles for gemm1

typedef __bf16 bf16x8 __attribute__((ext_vector_type(8)));
typedef float f32x4 __attribute__((ext_vector_type(4)));
typedef int int4v __attribute__((ext_vector_type(4)));

__device__ __forceinline__ unsigned short f2bf(float f) {
  unsigned u = __builtin_bit_cast(unsigned, f);
  u = (u + 0x7fffu + ((u >> 16) & 1u)) >> 16;
  return (unsigned short)u;
}
__device__ __forceinline__ float bf2f(unsigned short h) {
  unsigned u = ((unsigned)h) << 16;
  return __builtin_bit_cast(float, u);
}

__device__ __forceinline__ void gload16(void* lds, const void* g) {
  __builtin_amdgcn_global_load_lds(
      (const __attribute__((address_space(1))) unsigned int*)g,
      (__attribute__((address_space(3))) unsigned int*)lds, 16, 0, 0);
}

// ---------------- fp32 -> bf16 conversion ----------------
__global__ void k_f2b(const float* __restrict__ in, unsigned short* __restrict__ out, int n4) {
  for (int i = blockIdx.x * 256 + threadIdx.x; i < n4; i += gridDim.x * 256) {
    float4 v = ((const float4*)in)[i];
    ushort4 o;
    o.x = f2bf(v.x); o.y = f2bf(v.y); o.z = f2bf(v.z); o.w = f2bf(v.w);
    ((ushort4*)out)[i] = o;
  }
}

// ---------------- transpose linear_self (5760x3840 f32) -> T (3840x5760 bf16) ----------------
__global__ __launch_bounds__(256) void k_transpose(const float* __restrict__ LS,
                                                   unsigned short* __restrict__ T) {
  __shared__ float tile[32][33];
  int tx = threadIdx.x & 31, ty = threadIdx.x >> 5;
  int c0 = blockIdx.x * 32;  // col of LS = row of T
  int r0 = blockIdx.y * 32;  // row of LS = col of T
  for (int i = ty; i < 32; i += 8)
    tile[i][tx] = LS[(size_t)(r0 + i) * LSC + c0 + tx];
  __syncthreads();
  for (int i = ty; i < 32; i += 8)
    T[(size_t)(c0 + i) * LSR + r0 + tx] = f2bf(tile[tx][i]);
}

// ---------------- count valid[:,0] ----------------
__global__ void k_count(const int* __restrict__ ci, float* __restrict__ out) {
  int n = blockIdx.x * 256 + threadIdx.x;
  float v = (n < NROW && ci[(size_t)n * NCB] >= 0) ? 1.f : 0.f;
  #pragma unroll
  for (int m = 1; m < 64; m <<= 1) v += __shfl_xor(v, m);
  if ((threadIdx.x & 63) == 0) atomicAdd(out + 1, v);
}

// ---------------- GEMM1: 256x256 tile, BK=64 (2 k-halves), 8 waves, counted vmcnt ----------------
// r7 skeleton with barrier #1 REMOVED: frag-reads/STAGE of one wave may overlap
// the MFMA cluster of another (single rendezvous per phase at barrier #2).
// Race audit: STAGE(P) writes the region last read at P-1; every wave's P-1
// frag reads complete before it passes barrier #2(P-1), which precedes any
// wave's STAGE(P). vmcnt accounting per-wave, unchanged from r7.
__global__ __launch_bounds__(512, 2) void k_gemm1(
    const unsigned short* __restrict__ A,   // predictor bf16 [NROW][PD]
    const unsigned short* __restrict__ B,   // W1 bf16 [NH][PD]
    const float* __restrict__ b1,
    unsigned short* __restrict__ H) {       // out [NROW][NH]
  __shared__ int4 Al[2][2][1024];   // 64 KB
  __shared__ int4 Bl[2][2][1024];   // 64 KB

  const int tid = threadIdx.x;
  const int lane = tid & 63;
  const int w = tid >> 6;             // 0..7
  const int wr = w >> 2, wc = w & 3;  // wave grid 2(M) x 4(N)
  const int l15 = lane & 15, hi = lane >> 4;
  const int w64 = tid & ~63;

  // XCD swizzle: grid 1536 = 64 mt x 24 nt; each XCD owns 3 nt (3MB B -> L2)
  const int bid = blockIdx.x;
  const int xcd = bid & 7, p = bid >> 3;   // p in [0,192)
  const int nt = xcd * 3 + p % 3;
  const int mt = p / 3;
  const int tm = mt * 256, tn = nt * 256;

  f32x4 acc[8][4] = {};

  auto STAGE = [&](int buf, int t, int kh) {
    const int kb = t * 64 + kh * 32;
    #pragma unroll
    for (int g = 0; g < 2; ++g) {
      const int slot = g * 512 + tid;
      const int row = slot >> 2;                       // 0..255
      const int lc = (slot & 3) ^ ((row >> 1) & 3);    // inverse-swizzled source col
      gload16(&Al[buf][kh][g * 512 + w64], A + (size_t)(tm + row) * PD + kb + lc * 8);
      gload16(&Bl[buf][kh][g * 512 + w64], B + (size_t)(tn + row) * PD + kb + lc * 8);
    }
  };

  // prologue: t0.kh0, t0.kh1, t1.kh0 -> 12 loads; wait oldest 4 (t0.kh0)
  STAGE(0, 0, 0);
  STAGE(0, 0, 1);
  STAGE(1, 1, 0);
  asm volatile("s_waitcnt vmcnt(8)" ::: "memory");
  __builtin_amdgcn_s_barrier();

  for (int t = 0; t < GNT; ++t) {
    const int buf = t & 1;
    #pragma unroll
    for (int kh = 0; kh < 2; ++kh) {
      // frag reads (swizzled)
      int4 af[8], bfr[4];
      #pragma unroll
      for (int mi = 0; mi < 8; ++mi) {
        const int row = wr * 128 + mi * 16 + l15;
        const int pc = hi ^ ((row >> 1) & 3);
        af[mi] = Al[buf][kh][row * 4 + pc];
      }
      #pragma unroll
      for (int ni = 0; ni < 4; ++ni) {
        const int row = wc * 64 + ni * 16 + l15;
        const int pc = hi ^ ((row >> 1) & 3);
        bfr[ni] = Bl[buf][kh][row * 4 + pc];
      }
      // stage (regions race-safe, r7 audit)
      if (kh == 0) {
        if (t + 1 < GNT) STAGE(buf ^ 1, t + 1, 1);
      } else {
        if (t + 2 < GNT) STAGE(buf, t + 2, 0);
      }
      // (barrier #1 removed — cross-wave LDS/VALU vs MFMA overlap)
      __builtin_amdgcn_s_setprio(1);
      #pragma unroll
      for (int mi = 0; mi < 8; ++mi)
        #pragma unroll
        for (int ni = 0; ni < 4; ++ni)
          acc[mi][ni] = __builtin_amdgcn_mfma_f32_16x16x32_bf16(
              __builtin_bit_cast(bf16x8, af[mi]), __builtin_bit_cast(bf16x8, bfr[ni]),
              acc[mi][ni], 0, 0, 0);
      __builtin_amdgcn_s_setprio(0);
      // counted drains (audited): A-phase needs t.kh1; B-phase needs (t+1).kh0
      if (kh == 0) {
        if (t < GNT - 1) asm volatile("s_waitcnt vmcnt(8)" ::: "memory");
        else             asm volatile("s_waitcnt vmcnt(0)" ::: "memory");
      } else {
        if (t < GNT - 2)      asm volatile("s_waitcnt vmcnt(8)" ::: "memory");
        else if (t == GNT - 2) asm volatile("s_waitcnt vmcnt(4)" ::: "memory");
      }
      __builtin_amdgcn_s_barrier();
    }
  }

  // epilogue: bias + NT store
  #pragma unroll
  for (int ni = 0; ni < 4; ++ni) {
    const int col = tn + wc * 64 + ni * 16 + l15;
    const float bb = b1[col];
    #pragma unroll
    for (int mi = 0; mi < 8; ++mi)
      #pragma unroll
      for (int reg = 0; reg < 4; ++reg) {
        const int row = tm + wr * 128 + mi * 16 + hi * 4 + reg;
        __builtin_nontemporal_store(f2bf(acc[mi][ni][reg] + bb),
                                    H + (size_t)row * NH + col);
      }
  }
}

// ---------------- self-pred gather: branch-free unrolled ----------------
template <int KM>
__device__ __forceinline__ void gather_chunk(
    const unsigned short* __restrict__ T, const int* idxrow,
    int oo, int bbv, float v[8]) {
  #pragma unroll
  for (int kc = 0; kc < KM; ++kc) {
    int c = idxrow[kc];
    float m = (c >= 0 && kc <= bbv) ? 1.f : 0.f;
    int cc = c < 0 ? 0 : (c >= CS ? CS - 1 : c);
    int4v tv = *(const int4v*)(T + (size_t)(kc * CS + cc) * LSR + oo);
    const unsigned short* ts = (const unsigned short*)&tv;
    #pragma unroll
    for (int e = 0; e < 8; ++e) v[e] = fmaf(m, bf2f(ts[e]), v[e]);
  }
}

// grid = dim3(3, SA_NBLK): x = 2048-col stripe (compile-time gather depth),
// y = 32-row block. 1536 blocks -> 6/CU. One 8-col chunk per thread per row.
__global__ __launch_bounds__(256) void k_selfadd(
    unsigned short* __restrict__ H,        // [NROW][NH] bf16, in-place
    const unsigned short* __restrict__ T,  // [LSC][LSR] bf16 (linear_self^T)
    const int* __restrict__ ci,
    float* __restrict__ partials) {        // [2][SA_NBLK][NH]
  __shared__ int idxs[SA_ROWS][NCB];
  const int tid = threadIdx.x;
  const int row0 = blockIdx.y * SA_ROWS;
  const int sx = blockIdx.x;               // 0..2, block-uniform
  for (int i = tid; i < SA_ROWS * NCB; i += 256)
    idxs[i >> 4][i & 15] = ci[(size_t)(row0 + (i >> 4)) * NCB + (i & 15)];
  __syncthreads();

  const int col0 = sx * 2048 + tid * 8;
  const int o = col0 - HD;
  const int oo = o < 0 ? 0 : o;
  const int bb = o < 0 ? -1 : o / HD;

  float cs[8] = {0}, cq[8] = {0};

  for (int rr = 0; rr < SA_ROWS; ++rr) {
    const size_t ro = (size_t)(row0 + rr) * NH;
    int4v hv = __builtin_nontemporal_load((const int4v*)(H + ro + col0));
    const unsigned short* hs = (const unsigned short*)&hv;
    float v[8];
    #pragma unroll
    for (int e = 0; e < 8; ++e) v[e] = bf2f(hs[e]);
    switch (sx) {  // block-uniform branch, compile-time gather depth
      case 0: gather_chunk<5>(T, idxs[rr], oo, bb, v); break;
      case 1: gather_chunk<10>(T, idxs[rr], oo, bb, v); break;
      default: gather_chunk<15>(T, idxs[rr], oo, bb, v); break;
    }
    unsigned short os[8];
    #pragma unroll
    for (int e = 0; e < 8; ++e) {
      float x = fmaxf(v[e], 0.f);
      unsigned short hb = f2bf(x);
      os[e] = hb;
      float xr = bf2f(hb);
      cs[e] += xr;
      cq[e] += xr * xr;
    }
    // NT store: keep T resident in L2/L3; passc re-fetches H from HBM anyway
    __builtin_nontemporal_store(*(const int4v*)os, (int4v*)(H + ro + col0));
  }

  float* Ps = partials + (size_t)blockIdx.y * NH + col0;
  float* Pq = partials + (size_t)(SA_NBLK + blockIdx.y) * NH + col0;
  float4 a = {cs[0], cs[1], cs[2], cs[3]};
  float4 b4 = {cs[4], cs[5], cs[6], cs[7]};
  *(float4*)Ps = a; *(float4*)(Ps + 4) = b4;
  float4 c4 = {cq[0], cq[1], cq[2], cq[3]};
  float4 d4 = {cq[4], cq[5], cq[6], cq[7]};
  *(float4*)Pq = c4; *(float4*)(Pq + 4) = d4;
}

// ---------------- reduce partials -> colsum/colsq ----------------
// grid dim3(NH/256, 8)
__global__ void k_red(const float* __restrict__ partials,
                      float* __restrict__ colsum, float* __restrict__ colsq) {
  int j = blockIdx.x * 256 + threadIdx.x;
  const float* Ps = partials;
  const float* Pq = partials + (size_t)SA_NBLK * NH;
  float s = 0.f, q = 0.f;
  const int b0 = blockIdx.y * (SA_NBLK / 8), b1 = b0 + SA_NBLK / 8;
  for (int by = b0; by < b1; ++by) {
    s += Ps[(size_t)by * NH + j];
    q += Pq[(size_t)by * NH + j];
  }
  atomicAdd(colsum + j, s);
  atomicAdd(colsq + j, q);
}

// ---------------- BN params ----------------
__global__ void k_bn(const float* __restrict__ colsum, const float* __restrict__ colsq,
                     const float* __restrict__ gamma, const float* __restrict__ beta,
                     float* __restrict__ scale, float* __restrict__ shift) {
  int j = blockIdx.x * 256 + threadIdx.x;
  if (j >= NH) return;
  float mean = colsum[j] * (1.f / NROW);
  float var = colsq[j] * (1.f / NROW) - mean * mean;
  var = fmaxf(var, 0.f);
  float rs = rsqrtf(var + 1e-5f);
  float g = gamma[j] * rs;
  scale[j] = g;
  shift[j] = beta[j] - mean * g;
}

// ---------------- fold BN into linear2/bias2 ----------------
__global__ __launch_bounds__(128) void k_fold(
    const float* __restrict__ L2, const float* __restrict__ bias2,
    const float* __restrict__ scale, const float* __restrict__ shift,
    unsigned short* __restrict__ L2b, float* __restrict__ bias2p) {
  __shared__ float red[2];
  int kc = blockIdx.x;        // k*256 + c
  int k = kc >> 8;
  size_t off = (size_t)kc * HD;
  float a = 0.f;
  for (int h = threadIdx.x; h < HD; h += 128) {
    float wv = L2[off + h];
    int jh = k * HD + h;
    L2b[off + h] = f2bf(wv * scale[jh]);
    a += wv * shift[jh];
  }
  #pragma unroll
  for (int m = 1; m < 64; m <<= 1) a += __shfl_xor(a, m);
  if ((threadIdx.x & 63) == 0) red[threadIdx.x >> 6] = a;
  __syncthreads();
  if (threadIdx.x == 0) bias2p[kc] = bias2[kc] + red[0] + red[1];
}

// ---------------- pass C: logits GEMM + log-softmax + target gather ----------------
// grid dim3(256,16); XCD swizzle (2 codebooks/XCD -> L2b L2-resident);
// T3-minimum double-buffer: STAGE(next) issued before frag-read/MFMA(cur),
// single drain+barrier per K-step. LDS 66.5KB -> 2 blocks/CU overlap.
__global__ __launch_bounds__(256, 2) void k_passc(
    const unsigned short* __restrict__ H,     // [NROW][NH] bf16
    const unsigned short* __restrict__ L2b,   // [NCB][CS][HD] bf16 (BN-folded)
    const float* __restrict__ bias2p,         // [NCB][CS]
    const int* __restrict__ ci,
    float* __restrict__ out) {
  __shared__ char smem[64 * 260 * 4];  // 66560B; staging dbuf (40KB) aliased under lg
  __shared__ float red[4];
  float* lg = (float*)smem;            // [64][260]

  const int tid = threadIdx.x, lane = tid & 63, w = tid >> 6;
  const int bidf = blockIdx.y * gridDim.x + blockIdx.x;  // 0..4095
  const int xcd = bidf & 7, p = bidf >> 3;               // p in [0,512)
  const int k = xcd * 2 + (p & 1);
  const int tm = (p >> 1) * 64;
  const int r = lane & 15, kg = lane >> 4;

  auto Asb = [&](int buf) { return (int4*)(smem + buf * 20480); };          // 4KB
  auto Bsb = [&](int buf) { return (int4*)(smem + buf * 20480 + 4096); };   // 16KB

  const int s0r = (w * 64 + lane) & 63, s0g = (w * 64 + lane) >> 6;
  auto STAGE = [&](int buf, int kk) {
    const int k0 = kk * 32;
    gload16(Asb(buf) + w * 64, H + (size_t)(tm + s0r) * NH + k * HD + k0 + s0g * 8);
    #pragma unroll
    for (int i = 0; i < 4; ++i) {
      int s = i * 256 + w * 64 + lane;
      int srow = s & 255, skg = s >> 8;
      gload16(Bsb(buf) + i * 256 + w * 64,
              L2b + (size_t)(k * CS + srow) * HD + k0 + skg * 8);
    }
  };

  f32x4 acc[4][4] = {};
  int buf = 0;
  STAGE(0, 0);
  asm volatile("s_waitcnt vmcnt(0)" ::: "memory");
  __syncthreads();

  for (int kk = 0; kk < HD / 32; ++kk) {  // 12 steps
    if (kk + 1 < HD / 32) STAGE(buf ^ 1, kk + 1);   // 5 loads in flight during compute
    int4 af[4], bfr[4];
    #pragma unroll
    for (int mi = 0; mi < 4; ++mi) af[mi] = Asb(buf)[kg * 64 + mi * 16 + r];
    #pragma unroll
    for (int ni = 0; ni < 4; ++ni) bfr[ni] = Bsb(buf)[kg * 256 + w * 64 + ni * 16 + r];
    #pragma unroll
    for (int mi = 0; mi < 4; ++mi)
      #pragma unroll
      for (int ni = 0; ni < 4; ++ni)
        acc[mi][ni] = __builtin_amdgcn_mfma_f32_16x16x32_bf16(
            __builtin_bit_cast(bf16x8, af[mi]), __builtin_bit_cast(bf16x8, bfr[ni]),
            acc[mi][ni], 0, 0, 0);
    __syncthreads();   // drains vmcnt (staged loads had full MFMA window to land)
    buf ^= 1;
  }

  const int lr0 = (lane >> 4) * 4;
  #pragma unroll
  for (int mi = 0; mi < 4; ++mi)
    #pragma unroll
    for (int ni = 0; ni < 4; ++ni) {
      int col = w * 64 + ni * 16 + r;
      float bb = bias2p[k * CS + col];
      #pragma unroll
      for (int reg = 0; reg < 4; ++reg) {
        int row = mi * 16 + lr0 + reg;
        lg[row * 260 + col] = acc[mi][ni][reg] + bb;
      }
    }
  __syncthreads();

  int row = tid >> 2, part = tid & 3;
  const float4* rp = (const float4*)(lg + row * 260 + part * 64);
  float m = -1e30f;
  #pragma unroll
  for (int i = 0; i < 16; ++i) {
    float4 v = rp[i];
    m = fmaxf(m, fmaxf(fmaxf(v.x, v.y), fmaxf(v.z, v.w)));
  }
  m = fmaxf(m, __shfl_xor(m, 1));
  m = fmaxf(m, __shfl_xor(m, 2));
  float s = 0.f;
  #pragma unroll
  for (int i = 0; i < 16; ++i) {
    float4 v = rp[i];
    s += __expf(v.x - m) + __expf(v.y - m) + __expf(v.z - m) + __expf(v.w - m);
  }
  s += __shfl_xor(s, 1);
  s += __shfl_xor(s, 2);
  float contrib = 0.f;
  if (part == 0) {
    float lse = m + __logf(s);
    int c = ci[(size_t)(tm + row) * NCB + k];
    if (c >= 0) {
      c = c < CS ? c : CS - 1;
      contrib = lg[row * 260 + c] - lse;
    }
  }
  #pragma unroll
  for (int msk = 1; msk < 64; msk <<= 1) contrib += __shfl_xor(contrib, msk);
  if (lane == 0) red[w] = contrib;
  __syncthreads();
  if (tid == 0) atomicAdd(out, red[0] + red[1] + red[2] + red[3]);
}

extern "C" void kernel_launch(void* const* d_in, const int* in_sizes, int n_in,
                              void* d_out, int out_size, void* d_ws, size_t ws_size,
                              hipStream_t stream) {
  const float* predictor = (const float*)d_in[0];
  const int* cbidx       = (const int*)d_in[1];
  const float* W1        = (const float*)d_in[2];
  const float* b1        = (const float*)d_in[3];
  const float* lself     = (const float*)d_in[4];
  const float* gamma     = (const float*)d_in[5];
  const float* beta      = (const float*)d_in[6];
  const float* L2        = (const float*)d_in[7];
  const float* bias2     = (const float*)d_in[8];
  float* out = (float*)d_out;

  char* ws = (char*)d_ws;
  size_t off = 0;
  auto alloc = [&](size_t bytes) {
    char* p = ws + off;
    off += (bytes + 255) & ~(size_t)255;
    return p;
  };
  unsigned short* predB  = (unsigned short*)alloc((size_t)NROW * PD * 2);
  unsigned short* W1B    = (unsigned short*)alloc((size_t)NH * PD * 2);
  unsigned short* T      = (unsigned short*)alloc((size_t)LSC * LSR * 2);
  unsigned short* Hb     = (unsigned short*)alloc((size_t)NROW * NH * 2);
  unsigned short* L2b    = (unsigned short*)alloc((size_t)NCB * CS * HD * 2);
  float* partials = (float*)alloc((size_t)2 * SA_NBLK * NH * 4);
  float* colsum = (float*)alloc(NH * 4);
  float* colsq  = (float*)alloc(NH * 4);
  float* scale  = (float*)alloc(NH * 4);
  float* shift  = (float*)alloc(NH * 4);
  float* bias2p = (float*)alloc(NCB * CS * 4);

  hipMemsetAsync(d_out, 0, 2 * sizeof(float), stream);
  hipMemsetAsync(colsum, 0, NH * 4, stream);
  hipMemsetAsync(colsq, 0, NH * 4, stream);

  k_f2b<<<2048, 256, 0, stream>>>(predictor, predB, NROW * PD / 4);
  k_f2b<<<2048, 256, 0, stream>>>(W1, W1B, NH * PD / 4);
  k_transpose<<<dim3(LSC / 32, LSR / 32), 256, 0, stream>>>(lself, T);
  k_count<<<NROW / 256, 256, 0, stream>>>(cbidx, out);
  k_gemm1<<<(NROW / 256) * (NH / 256), 512, 0, stream>>>(predB, W1B, b1, Hb);
  k_selfadd<<<dim3(3, SA_NBLK), 256, 0, stream>>>(Hb, T, cbidx, partials);
  k_red<<<dim3(NH / 256, 8), 256, 0, stream>>>(partials, colsum, colsq);
  k_bn<<<NH / 256, 256, 0, stream>>>(colsum, colsq, gamma, beta, scale, shift);
  k_fold<<<NCB * CS, 128, 0, stream>>>(L2, bias2, scale, shift, L2b, bias2p);
  k_passc<<<dim3(NROW / 64, NCB), 256, 0, stream>>>(Hb, L2b, bias2p, cbidx, out);
}